// Round 10
// baseline (325.983 us; speedup 1.0000x reference)
//
#include <hip/hip_runtime.h>

#define N_NODES 100000
#define N_EDGES 50000
#define N_KEYS  150000   // node keys [0,100000) then edge keys [100000,150000)
#define M_INC   1600000
#define D_HID   64

#define SUBR    32       // incidence subranges
#define SUBLEN  50000    // M_INC / SUBR
#define KPART   16384    // keys per LDS partition (64 KB histogram)
#define PN      7        // ceil(100000/16384)
#define PE      4        // ceil(50000/16384)

#define N_TILES_N 25   // ceil(100000/4096)
#define N_TILES_E 13   // ceil(50000/4096)

typedef int   v4i __attribute__((ext_vector_type(4)));
typedef float v4f __attribute__((ext_vector_type(4)));

// ---- workspace layout (byte offsets, lifetime-overlapped) ----
// noff  [100001 int] @ 0        ; eoff [50001 int] @ 400016
// csr_n [1.6M u16]   @ 600032   (edge ids grouped by node)  \ cnt_g u16 [9.6MB]
// csr_e [1.6M u32]   @ 3800032  (node ids grouped by edge)  / overlays @600032
//                                                             (dead before fill)
// ef bf16 [6.4MB]    @ 10200032 (stage1 output)
// xh bf16 [12.8MB]   @ 16600032 (cvt output, post-fill)
//   rb u16 [9.6MB] overlays @16600032 (dead after fill); tot @26200032;
//   scan scratch @26800032 — all dead before cvt writes xh.

__device__ __forceinline__ unsigned pack2bf(float a, float b) {
    unsigned ua = __float_as_uint(a); ua = (ua + 0x7fffu + ((ua >> 16) & 1u)) >> 16;
    unsigned ub = __float_as_uint(b); ub = (ub + 0x7fffu + ((ub >> 16) & 1u)) >> 16;
    return ua | (ub << 16);
}

// Count: block (p,s) filters subrange s for keys in partition p, LDS histogram,
// dumps per-(s,key) counts. No rank storage (fill re-derives ranks).
__global__ __launch_bounds__(1024) void count_kernel(
        const int* __restrict__ node_idx, const int* __restrict__ edge_idx,
        unsigned short* __restrict__ cnt_g) {
    __shared__ unsigned int h[KPART];
    int bid = blockIdx.x;
    const int* idx; int p, s, klim, goff;
    if (bid < PN * SUBR) {
        p = bid / SUBR; s = bid % SUBR;
        idx = node_idx; klim = N_NODES; goff = 0;
    } else {
        int b2 = bid - PN * SUBR;
        p = b2 / SUBR; s = b2 % SUBR;
        idx = edge_idx; klim = N_EDGES; goff = N_NODES;
    }
    int kbase = p * KPART;
    int t = threadIdx.x;
    for (int i = t; i < KPART; i += 1024) h[i] = 0;
    __syncthreads();
    const v4i* src4 = (const v4i*)(idx + s * SUBLEN);
    for (int i = t; i < SUBLEN / 4; i += 1024) {
        v4i v = __builtin_nontemporal_load(&src4[i]);
        int k;
        k = v.x - kbase; if ((unsigned)k < KPART) atomicAdd(&h[k], 1u);
        k = v.y - kbase; if ((unsigned)k < KPART) atomicAdd(&h[k], 1u);
        k = v.z - kbase; if ((unsigned)k < KPART) atomicAdd(&h[k], 1u);
        k = v.w - kbase; if ((unsigned)k < KPART) atomicAdd(&h[k], 1u);
    }
    __syncthreads();
    for (int i = t; i < KPART; i += 1024) {
        int key = kbase + i;
        if (key < klim) cnt_g[s * N_KEYS + goff + key] = (unsigned short)h[i];
    }
}

// Per-key prefix over the 32 subrange counts -> rb[s][key] (u16); totals -> tot.
__global__ void replprefix_kernel(const unsigned short* __restrict__ cnt_g,
                                  unsigned short* __restrict__ rb, int* __restrict__ tot) {
    int key = blockIdx.x * 256 + threadIdx.x;
    if (key < N_KEYS) {
        int base = 0;
#pragma unroll
        for (int k = 0; k < SUBR; k++) {
            rb[k * N_KEYS + key] = (unsigned short)base;
            base += (int)cnt_g[k * N_KEYS + key];
        }
        tot[key] = base;
    }
}

// Scan stage 1: per-tile (4096) sums over the totals array.
__global__ void scan_partial_kernel(const int* __restrict__ cnt,
                                    int* __restrict__ pn, int* __restrict__ pe) {
    __shared__ int lds[16];
    int b = blockIdx.x;
    const int* src; int nElem; int tile; int* dst;
    if (b < N_TILES_N) { src = cnt;            nElem = N_NODES; tile = b;             dst = pn; }
    else               { src = cnt + N_NODES;  nElem = N_EDGES; tile = b - N_TILES_N; dst = pe; }
    int t = threadIdx.x;
    int i4 = tile * 1024 + t;
    int sum = 0;
    if (i4 * 4 < nElem) {
        int4 v = ((const int4*)src)[i4];
        sum = v.x + v.y + v.z + v.w;
    }
    for (int off = 1; off < 64; off <<= 1) sum += __shfl_xor(sum, off, 64);
    if ((t & 63) == 0) lds[t >> 6] = sum;
    __syncthreads();
    if (t < 16) {
        int s = lds[t];
        for (int off = 1; off < 16; off <<= 1) s += __shfl_xor(s, off, 64);
        if (t == 0) dst[tile] = s;
    }
}

// Scan stage 2: exclusive scan of tile sums; writes sentinel offsets.
__global__ void scan_base_kernel(const int* __restrict__ pn, const int* __restrict__ pe,
                                 int* __restrict__ bn, int* __restrict__ be,
                                 int* __restrict__ noff, int* __restrict__ eoff) {
    int w = threadIdx.x >> 6;
    int lane = threadIdx.x & 63;
    if (w == 0) {
        int v = (lane < N_TILES_N) ? pn[lane] : 0;
        int incl = v;
        for (int d = 1; d < 64; d <<= 1) { int u = __shfl_up(incl, d, 64); if (lane >= d) incl += u; }
        if (lane < N_TILES_N) bn[lane] = incl - v;
        if (lane == N_TILES_N - 1) noff[N_NODES] = incl;
    } else {
        int v = (lane < N_TILES_E) ? pe[lane] : 0;
        int incl = v;
        for (int d = 1; d < 64; d <<= 1) { int u = __shfl_up(incl, d, 64); if (lane >= d) incl += u; }
        if (lane < N_TILES_E) be[lane] = incl - v;
        if (lane == N_TILES_E - 1) eoff[N_EDGES] = incl;
    }
}

// Scan stage 3: block-level exclusive scan of each tile + tile base, int4 I/O.
__global__ void scan_write_kernel(const int* __restrict__ cnt,
                                  const int* __restrict__ bn, const int* __restrict__ be,
                                  int* __restrict__ noff, int* __restrict__ eoff) {
    __shared__ int wsum[16];
    int b = blockIdx.x;
    const int* src; int* dst; int nElem; int tile; int tbase;
    if (b < N_TILES_N) { src = cnt;           dst = noff; nElem = N_NODES; tile = b;             tbase = bn[tile]; }
    else               { src = cnt + N_NODES; dst = eoff; nElem = N_EDGES; tile = b - N_TILES_N; tbase = be[tile]; }
    int t = threadIdx.x;
    int lane = t & 63, w = t >> 6;
    int i4 = tile * 1024 + t;
    int4 c = make_int4(0, 0, 0, 0);
    bool valid = (i4 * 4 < nElem);
    if (valid) c = ((const int4*)src)[i4];
    int tsum = c.x + c.y + c.z + c.w;
    int incl = tsum;
    for (int d = 1; d < 64; d <<= 1) { int u = __shfl_up(incl, d, 64); if (lane >= d) incl += u; }
    if (lane == 63) wsum[w] = incl;
    __syncthreads();
    if (t < 16) {
        int v = wsum[t];
        int wi = v;
        for (int d = 1; d < 16; d <<= 1) { int u = __shfl_up(wi, d, 64); if (t >= d) wi += u; }
        wsum[t] = wi - v;
    }
    __syncthreads();
    int ex = tbase + wsum[w] + incl - tsum;
    if (valid) {
        int4 o;
        o.x = ex; o.y = ex + c.x; o.z = o.y + c.y; o.w = o.z + c.z;
        ((int4*)dst)[i4] = o;
    }
}

// Fill: partitioned scatter with LDS-rederived ranks. All writes for a
// partition land in a 0.5-2MB CSR window; partitions are pinned to XCDs via
// the blockIdx%8 dispatch heuristic so partial lines coalesce in one L2.
// Load-balanced table: edge partitions (2x work) alone on XCDs 0-3,
// node partitions paired on XCDs 4-7.
__global__ __launch_bounds__(1024) void fill_kernel(
        const int* __restrict__ node_idx, const int* __restrict__ edge_idx,
        const unsigned short* __restrict__ rb,
        const int* __restrict__ noff, const int* __restrict__ eoff,
        unsigned short* __restrict__ csr_n, unsigned int* __restrict__ csr_e) {
    __shared__ unsigned int h[KPART];
    // partition id 0..6 = node, 7..10 = edge(p-7)
    const int part0[8] = {7, 8, 9, 10, 0, 2, 4, 6};
    const int part1[8] = {-1, -1, -1, -1, 1, 3, 5, -1};
    int g = blockIdx.x & 7;
    int j = blockIdx.x >> 3;           // 0..63
    int p = (j < 32) ? part0[g] : part1[g];
    if (p < 0) return;
    int s = j & 31;
    int t = threadIdx.x;
    for (int i = t; i < KPART; i += 1024) h[i] = 0;
    __syncthreads();
    int mbase = s * SUBLEN;
    if (p < PN) {  // node side: key=node, value=edge (u16)
        int kbase = p * KPART;
        const v4i* k4 = (const v4i*)(node_idx + mbase);
        const v4i* v4 = (const v4i*)(edge_idx + mbase);
        const unsigned short* rbs = rb + s * N_KEYS;
        for (int i = t; i < SUBLEN / 4; i += 1024) {
            v4i kv = __builtin_nontemporal_load(&k4[i]);
            v4i vv = __builtin_nontemporal_load(&v4[i]);
            int k;
            k = kv.x - kbase; if ((unsigned)k < KPART) { unsigned r = atomicAdd(&h[k], 1u); csr_n[noff[kv.x] + (int)rbs[kv.x] + (int)r] = (unsigned short)vv.x; }
            k = kv.y - kbase; if ((unsigned)k < KPART) { unsigned r = atomicAdd(&h[k], 1u); csr_n[noff[kv.y] + (int)rbs[kv.y] + (int)r] = (unsigned short)vv.y; }
            k = kv.z - kbase; if ((unsigned)k < KPART) { unsigned r = atomicAdd(&h[k], 1u); csr_n[noff[kv.z] + (int)rbs[kv.z] + (int)r] = (unsigned short)vv.z; }
            k = kv.w - kbase; if ((unsigned)k < KPART) { unsigned r = atomicAdd(&h[k], 1u); csr_n[noff[kv.w] + (int)rbs[kv.w] + (int)r] = (unsigned short)vv.w; }
        }
    } else {       // edge side: key=edge, value=node (u32)
        int kbase = (p - PN) * KPART;
        const v4i* k4 = (const v4i*)(edge_idx + mbase);
        const v4i* v4 = (const v4i*)(node_idx + mbase);
        const unsigned short* rbs = rb + s * N_KEYS + N_NODES;
        for (int i = t; i < SUBLEN / 4; i += 1024) {
            v4i kv = __builtin_nontemporal_load(&k4[i]);
            v4i vv = __builtin_nontemporal_load(&v4[i]);
            int k;
            k = kv.x - kbase; if ((unsigned)k < KPART) { unsigned r = atomicAdd(&h[k], 1u); csr_e[eoff[kv.x] + (int)rbs[kv.x] + (int)r] = (unsigned)vv.x; }
            k = kv.y - kbase; if ((unsigned)k < KPART) { unsigned r = atomicAdd(&h[k], 1u); csr_e[eoff[kv.y] + (int)rbs[kv.y] + (int)r] = (unsigned)vv.y; }
            k = kv.z - kbase; if ((unsigned)k < KPART) { unsigned r = atomicAdd(&h[k], 1u); csr_e[eoff[kv.z] + (int)rbs[kv.z] + (int)r] = (unsigned)vv.z; }
            k = kv.w - kbase; if ((unsigned)k < KPART) { unsigned r = atomicAdd(&h[k], 1u); csr_e[eoff[kv.w] + (int)rbs[kv.w] + (int)r] = (unsigned)vv.w; }
        }
    }
}

// Convert x (fp32) -> xh (bf16, RNE). 8 elements / thread, coalesced.
__global__ void cvt_kernel(const float* __restrict__ x, unsigned int* __restrict__ xh) {
    int i = blockIdx.x * 256 + threadIdx.x;
    if (i < (N_NODES * D_HID) / 8) {
        const float4* x4 = (const float4*)x;
        float4 a = x4[i * 2], b = x4[i * 2 + 1];
        uint4 o;
        o.x = pack2bf(a.x, a.y); o.y = pack2bf(a.z, a.w);
        o.z = pack2bf(b.x, b.y); o.w = pack2bf(b.z, b.w);
        ((uint4*)xh)[i] = o;
    }
}

// Stage 1: one wave per edge; 8 member-groups x 8 lanes, 16B (8 bf16) per lane.
__global__ void stage1_kernel(const int* __restrict__ eoff, const unsigned int* __restrict__ ecsr,
                              const uint4* __restrict__ xh, uint4* __restrict__ ef) {
    int wid = (blockIdx.x * 256 + threadIdx.x) >> 6;
    if (wid >= N_EDGES) return;
    int lane = threadIdx.x & 63;
    int group = lane >> 3;
    int gl = lane & 7;
    int s = eoff[wid], t = eoff[wid + 1];
    float acc[8] = {0.f, 0.f, 0.f, 0.f, 0.f, 0.f, 0.f, 0.f};
    for (int base = s; base < t; base += 64) {
        int idx_l = (base + lane < t) ? (int)__builtin_nontemporal_load(&ecsr[base + lane]) : 0;
        int cnt = t - base; if (cnt > 64) cnt = 64;
        int steps = (cnt + 7) >> 3;
        for (int j = 0; j < steps; j++) {
            int pp = 8 * j + group;
            int mi = __shfl(idx_l, pp, 64);
            if (pp < cnt) {
                uint4 v = xh[(size_t)mi * 8 + gl];
                acc[0] += __uint_as_float(v.x << 16); acc[1] += __uint_as_float(v.x & 0xffff0000u);
                acc[2] += __uint_as_float(v.y << 16); acc[3] += __uint_as_float(v.y & 0xffff0000u);
                acc[4] += __uint_as_float(v.z << 16); acc[5] += __uint_as_float(v.z & 0xffff0000u);
                acc[6] += __uint_as_float(v.w << 16); acc[7] += __uint_as_float(v.w & 0xffff0000u);
            }
        }
    }
    for (int off = 8; off < 64; off <<= 1)
#pragma unroll
        for (int i = 0; i < 8; i++) acc[i] += __shfl_xor(acc[i], off, 64);
    if (group == 0) {
        int card = t - s;
        float ber = (card > 0) ? (1.0f / (float)card) : 0.f;
        uint4 o;
        o.x = pack2bf(acc[0] * ber, acc[1] * ber);
        o.y = pack2bf(acc[2] * ber, acc[3] * ber);
        o.z = pack2bf(acc[4] * ber, acc[5] * ber);
        o.w = pack2bf(acc[6] * ber, acc[7] * ber);
        ef[(size_t)wid * 8 + gl] = o;
    }
}

// Stage 2: one wave per node; bf16 ef gathers, u16 csr, fp32 residual/output.
__global__ void stage2_kernel(const int* __restrict__ noff, const unsigned short* __restrict__ ncsr,
                              const uint4* __restrict__ ef, const float* __restrict__ ew,
                              const float* __restrict__ x, float* __restrict__ out) {
    int wid = (blockIdx.x * 256 + threadIdx.x) >> 6;
    if (wid >= N_NODES) return;
    int lane = threadIdx.x & 63;
    int group = lane >> 3;
    int gl = lane & 7;
    int s = noff[wid], t = noff[wid + 1];
    float acc[8] = {0.f, 0.f, 0.f, 0.f, 0.f, 0.f, 0.f, 0.f};
    float dn = 0.f;
    for (int base = s; base < t; base += 64) {
        bool lv = (base + lane < t);
        int idx_l = lv ? (int)__builtin_nontemporal_load(&ncsr[base + lane]) : 0;
        if (lv) dn += ew[idx_l];
        int cnt = t - base; if (cnt > 64) cnt = 64;
        int steps = (cnt + 7) >> 3;
        for (int j = 0; j < steps; j++) {
            int pp = 8 * j + group;
            int mi = __shfl(idx_l, pp, 64);
            if (pp < cnt) {
                uint4 v = ef[(size_t)mi * 8 + gl];
                acc[0] += __uint_as_float(v.x << 16); acc[1] += __uint_as_float(v.x & 0xffff0000u);
                acc[2] += __uint_as_float(v.y << 16); acc[3] += __uint_as_float(v.y & 0xffff0000u);
                acc[4] += __uint_as_float(v.z << 16); acc[5] += __uint_as_float(v.z & 0xffff0000u);
                acc[6] += __uint_as_float(v.w << 16); acc[7] += __uint_as_float(v.w & 0xffff0000u);
            }
        }
    }
    for (int off = 1; off < 64; off <<= 1) dn += __shfl_xor(dn, off, 64);
    for (int off = 8; off < 64; off <<= 1)
#pragma unroll
        for (int i = 0; i < 8; i++) acc[i] += __shfl_xor(acc[i], off, 64);
    if (group == 0) {
        float dnr = (dn > 0.f) ? (1.0f / dn) : 0.f;
        const float4* x4 = (const float4*)x;
        float4 a = x4[(size_t)wid * 16 + gl * 2];
        float4 b = x4[(size_t)wid * 16 + gl * 2 + 1];
        v4f ra, rb2;
        ra.x = 0.5f * (a.x + dnr * acc[0]);
        ra.y = 0.5f * (a.y + dnr * acc[1]);
        ra.z = 0.5f * (a.z + dnr * acc[2]);
        ra.w = 0.5f * (a.w + dnr * acc[3]);
        rb2.x = 0.5f * (b.x + dnr * acc[4]);
        rb2.y = 0.5f * (b.y + dnr * acc[5]);
        rb2.z = 0.5f * (b.z + dnr * acc[6]);
        rb2.w = 0.5f * (b.w + dnr * acc[7]);
        __builtin_nontemporal_store(ra, &((v4f*)out)[(size_t)wid * 16 + gl * 2]);
        __builtin_nontemporal_store(rb2, &((v4f*)out)[(size_t)wid * 16 + gl * 2 + 1]);
    }
}

extern "C" void kernel_launch(void* const* d_in, const int* in_sizes, int n_in,
                              void* d_out, int out_size, void* d_ws, size_t ws_size,
                              hipStream_t stream) {
    const float* x        = (const float*)d_in[0];
    const int*   node_idx = (const int*)d_in[1];
    const int*   edge_idx = (const int*)d_in[2];
    const float* ew       = (const float*)d_in[3];
    float* out = (float*)d_out;

    char* ws = (char*)d_ws;
    int*            noff  = (int*)(ws + 0);
    int*            eoff  = (int*)(ws + 400016);
    unsigned short* csr_n = (unsigned short*)(ws + 600032);
    unsigned int*   csr_e = (unsigned int*)(ws + 3800032);
    unsigned int*   ef    = (unsigned int*)(ws + 10200032);
    unsigned int*   xh    = (unsigned int*)(ws + 16600032);
    // lifetime-overlapped scratch:
    unsigned short* cnt_g = (unsigned short*)(ws + 600032);   // 9.6MB over csr; dead before fill
    unsigned short* rb    = (unsigned short*)(ws + 16600032); // 9.6MB over xh; dead before cvt
    int*            tot   = (int*)(ws + 26200032);            // 600KB
    int*            pn    = (int*)(ws + 26800032);
    int*            pe    = pn + 32;
    int*            bn    = pn + 64;
    int*            be    = pn + 96;

    count_kernel<<<(PN + PE) * SUBR, 1024, 0, stream>>>(node_idx, edge_idx, cnt_g);
    replprefix_kernel<<<(N_KEYS + 255) / 256, 256, 0, stream>>>(cnt_g, rb, tot);
    scan_partial_kernel<<<N_TILES_N + N_TILES_E, 1024, 0, stream>>>(tot, pn, pe);
    scan_base_kernel<<<1, 128, 0, stream>>>(pn, pe, bn, be, noff, eoff);
    scan_write_kernel<<<N_TILES_N + N_TILES_E, 1024, 0, stream>>>(tot, bn, be, noff, eoff);
    fill_kernel<<<512, 1024, 0, stream>>>(node_idx, edge_idx, rb, noff, eoff, csr_n, csr_e);
    cvt_kernel<<<((N_NODES * D_HID / 8) + 255) / 256, 256, 0, stream>>>(x, xh);
    stage1_kernel<<<(N_EDGES * 64 + 255) / 256, 256, 0, stream>>>(eoff, csr_e,
                                                                  (const uint4*)xh, (uint4*)ef);
    stage2_kernel<<<(N_NODES * 64 + 255) / 256, 256, 0, stream>>>(noff, csr_n,
                                                                  (const uint4*)ef, ew, x, out);
}

// Round 11
// 303.601 us; speedup vs baseline: 1.0737x; 1.0737x over previous
//
#include <hip/hip_runtime.h>

#define N_NODES 100000
#define N_EDGES 50000
#define N_KEYS  150000   // node keys [0,100000) then edge keys [100000,150000)
#define M_INC   1600000
#define D_HID   64

#define SUBR    32       // incidence subranges
#define SUBLEN  50000    // M_INC / SUBR
#define KPART   16384    // keys per LDS partition (64 KB histogram)
#define PN      7        // ceil(100000/16384)
#define PE      4        // ceil(50000/16384)

#define N_TILES_N 25   // ceil(100000/4096)
#define N_TILES_E 13   // ceil(50000/4096)

typedef int v4i __attribute__((ext_vector_type(4)));

// ---- workspace layout (byte offsets, lifetime-overlapped) ----
// rank_n [1.6M u16] @0, rank_e @3200000            -- dead after fill
// ef bf16 [3.2M]    @0  (6.4MB)                    -- written by stage1 (post-fill)
// noff [100001 int] @6400000 ; eoff @6800016
// node_csr @7000032, edge_csr @13400032            -- cnt_g u16 [9.6MB] overlaps
//                                                     (dead after replprefix)
// rb u16 [9.6MB] @19800032, scan scratch @29400032 -- dead after fill / scan
// xh bf16 [6.4M] @19800032 (12.8MB)                -- written by cvt AFTER fill

__device__ __forceinline__ unsigned pack2bf(float a, float b) {
    unsigned ua = __float_as_uint(a); ua = (ua + 0x7fffu + ((ua >> 16) & 1u)) >> 16;
    unsigned ub = __float_as_uint(b); ub = (ub + 0x7fffu + ((ub >> 16) & 1u)) >> 16;
    return ua | (ub << 16);
}

// Counting without global atomics: block (p,s) filters subrange s for keys in
// partition p, LDS-atomicAdd gives the subrank (u16), then dumps its histogram.
// KPART=16K (64KB LDS): 11 partitions => 70MB re-read (vs 128MB @ 8K).
__global__ __launch_bounds__(1024) void count_kernel(
        const int* __restrict__ node_idx, const int* __restrict__ edge_idx,
        unsigned short* __restrict__ rank_n, unsigned short* __restrict__ rank_e,
        unsigned short* __restrict__ cnt_g) {
    __shared__ unsigned int h[KPART];
    int bid = blockIdx.x;
    const int* idx; unsigned short* rk; int p, s, klim, goff;
    if (bid < PN * SUBR) {
        p = bid / SUBR; s = bid % SUBR;
        idx = node_idx; rk = rank_n; klim = N_NODES; goff = 0;
    } else {
        int b2 = bid - PN * SUBR;
        p = b2 / SUBR; s = b2 % SUBR;
        idx = edge_idx; rk = rank_e; klim = N_EDGES; goff = N_NODES;
    }
    int kbase = p * KPART;
    int t = threadIdx.x;
    for (int i = t; i < KPART; i += 1024) h[i] = 0;
    __syncthreads();
    int mbase = s * SUBLEN;
    const v4i* src4 = (const v4i*)(idx + mbase);
    for (int i = t; i < SUBLEN / 4; i += 1024) {
        v4i v = __builtin_nontemporal_load(&src4[i]);
        int m0 = mbase + i * 4;
        int k;
        k = v.x - kbase; if ((unsigned)k < KPART) rk[m0 + 0] = (unsigned short)atomicAdd(&h[k], 1u);
        k = v.y - kbase; if ((unsigned)k < KPART) rk[m0 + 1] = (unsigned short)atomicAdd(&h[k], 1u);
        k = v.z - kbase; if ((unsigned)k < KPART) rk[m0 + 2] = (unsigned short)atomicAdd(&h[k], 1u);
        k = v.w - kbase; if ((unsigned)k < KPART) rk[m0 + 3] = (unsigned short)atomicAdd(&h[k], 1u);
    }
    __syncthreads();
    for (int i = t; i < KPART; i += 1024) {
        int key = kbase + i;
        if (key < klim) cnt_g[s * N_KEYS + goff + key] = (unsigned short)h[i];
    }
}

// Per-key prefix over the 32 subrange counts -> rb[s][key] (u16); totals -> tot[key].
__global__ void replprefix_kernel(const unsigned short* __restrict__ cnt_g,
                                  unsigned short* __restrict__ rb, int* __restrict__ tot) {
    int key = blockIdx.x * 256 + threadIdx.x;
    if (key < N_KEYS) {
        int base = 0;
#pragma unroll
        for (int k = 0; k < SUBR; k++) {
            rb[k * N_KEYS + key] = (unsigned short)base;
            base += (int)cnt_g[k * N_KEYS + key];
        }
        tot[key] = base;
    }
}

// Scan stage 1: per-tile (4096 elements) sums over the contiguous totals array.
__global__ void scan_partial_kernel(const int* __restrict__ cnt,
                                    int* __restrict__ pn, int* __restrict__ pe) {
    __shared__ int lds[16];
    int b = blockIdx.x;
    const int* src; int nElem; int tile; int* dst;
    if (b < N_TILES_N) { src = cnt;            nElem = N_NODES; tile = b;             dst = pn; }
    else               { src = cnt + N_NODES;  nElem = N_EDGES; tile = b - N_TILES_N; dst = pe; }
    int t = threadIdx.x;
    int i4 = tile * 1024 + t;
    int sum = 0;
    if (i4 * 4 < nElem) {
        int4 v = ((const int4*)src)[i4];
        sum = v.x + v.y + v.z + v.w;
    }
    for (int off = 1; off < 64; off <<= 1) sum += __shfl_xor(sum, off, 64);
    if ((t & 63) == 0) lds[t >> 6] = sum;
    __syncthreads();
    if (t < 16) {
        int s = lds[t];
        for (int off = 1; off < 16; off <<= 1) s += __shfl_xor(s, off, 64);
        if (t == 0) dst[tile] = s;
    }
}

// Scan stage 2: exclusive scan of tile sums; writes sentinel offsets.
__global__ void scan_base_kernel(const int* __restrict__ pn, const int* __restrict__ pe,
                                 int* __restrict__ bn, int* __restrict__ be,
                                 int* __restrict__ noff, int* __restrict__ eoff) {
    int w = threadIdx.x >> 6;
    int lane = threadIdx.x & 63;
    if (w == 0) {
        int v = (lane < N_TILES_N) ? pn[lane] : 0;
        int incl = v;
        for (int d = 1; d < 64; d <<= 1) { int u = __shfl_up(incl, d, 64); if (lane >= d) incl += u; }
        if (lane < N_TILES_N) bn[lane] = incl - v;
        if (lane == N_TILES_N - 1) noff[N_NODES] = incl;
    } else {
        int v = (lane < N_TILES_E) ? pe[lane] : 0;
        int incl = v;
        for (int d = 1; d < 64; d <<= 1) { int u = __shfl_up(incl, d, 64); if (lane >= d) incl += u; }
        if (lane < N_TILES_E) be[lane] = incl - v;
        if (lane == N_TILES_E - 1) eoff[N_EDGES] = incl;
    }
}

// Scan stage 3: block-level exclusive scan of each tile + tile base, int4 I/O.
__global__ void scan_write_kernel(const int* __restrict__ cnt,
                                  const int* __restrict__ bn, const int* __restrict__ be,
                                  int* __restrict__ noff, int* __restrict__ eoff) {
    __shared__ int wsum[16];
    int b = blockIdx.x;
    const int* src; int* dst; int nElem; int tile; int tbase;
    if (b < N_TILES_N) { src = cnt;           dst = noff; nElem = N_NODES; tile = b;             tbase = bn[tile]; }
    else               { src = cnt + N_NODES; dst = eoff; nElem = N_EDGES; tile = b - N_TILES_N; tbase = be[tile]; }
    int t = threadIdx.x;
    int lane = t & 63, w = t >> 6;
    int i4 = tile * 1024 + t;
    int4 c = make_int4(0, 0, 0, 0);
    bool valid = (i4 * 4 < nElem);
    if (valid) c = ((const int4*)src)[i4];
    int tsum = c.x + c.y + c.z + c.w;
    int incl = tsum;
    for (int d = 1; d < 64; d <<= 1) { int u = __shfl_up(incl, d, 64); if (lane >= d) incl += u; }
    if (lane == 63) wsum[w] = incl;
    __syncthreads();
    if (t < 16) {
        int v = wsum[t];
        int wi = v;
        for (int d = 1; d < 16; d <<= 1) { int u = __shfl_up(wi, d, 64); if (t >= d) wi += u; }
        wsum[t] = wi - v;
    }
    __syncthreads();
    int ex = tbase + wsum[w] + incl - tsum;
    if (valid) {
        int4 o;
        o.x = ex; o.y = ex + c.x; o.z = o.y + c.y; o.w = o.z + c.z;
        ((int4*)dst)[i4] = o;
    }
}

// Fill: atomic-free scatter. Slot = seg_off + subrange_base + subrank.
__global__ void fill_kernel(const int* __restrict__ node_idx,
                            const int* __restrict__ edge_idx,
                            const unsigned short* __restrict__ rank_n,
                            const unsigned short* __restrict__ rank_e,
                            const unsigned short* __restrict__ rb,
                            const int* __restrict__ noff, const int* __restrict__ eoff,
                            int* __restrict__ node_csr, int* __restrict__ edge_csr) {
    int m = blockIdx.x * 256 + threadIdx.x;
    if (m < M_INC) {
        int s = m / SUBLEN;
        const unsigned short* rbs = rb + s * N_KEYS;
        int n = node_idx[m], e = edge_idx[m];
        node_csr[noff[n] + (int)rbs[n] + (int)rank_n[m]] = e;
        edge_csr[eoff[e] + (int)rbs[N_NODES + e] + (int)rank_e[m]] = n;
    }
}

// Convert x (fp32) -> xh (bf16, RNE). 8 elements / thread, coalesced.
__global__ void cvt_kernel(const float* __restrict__ x, unsigned int* __restrict__ xh) {
    int i = blockIdx.x * 256 + threadIdx.x;           // 8-element group
    if (i < (N_NODES * D_HID) / 8) {
        const float4* x4 = (const float4*)x;
        float4 a = x4[i * 2], b = x4[i * 2 + 1];
        uint4 o;
        o.x = pack2bf(a.x, a.y); o.y = pack2bf(a.z, a.w);
        o.z = pack2bf(b.x, b.y); o.w = pack2bf(b.z, b.w);
        ((uint4*)xh)[i] = o;
    }
}

// Stage 1: one wave per edge; 8 member-groups x 8 lanes, 16B (8 bf16) per lane.
__global__ void stage1_kernel(const int* __restrict__ eoff, const int* __restrict__ ecsr,
                              const uint4* __restrict__ xh, uint4* __restrict__ ef) {
    int wid = (blockIdx.x * 256 + threadIdx.x) >> 6;
    if (wid >= N_EDGES) return;
    int lane = threadIdx.x & 63;
    int group = lane >> 3;
    int gl = lane & 7;
    int s = eoff[wid], t = eoff[wid + 1];
    float acc[8] = {0.f, 0.f, 0.f, 0.f, 0.f, 0.f, 0.f, 0.f};
    for (int base = s; base < t; base += 64) {
        int idx_l = (base + lane < t) ? ecsr[base + lane] : 0;
        int cnt = t - base; if (cnt > 64) cnt = 64;
        int steps = (cnt + 7) >> 3;
        for (int j = 0; j < steps; j++) {
            int p = 8 * j + group;
            int mi = __shfl(idx_l, p, 64);
            if (p < cnt) {
                uint4 v = xh[(size_t)mi * 8 + gl];
                acc[0] += __uint_as_float(v.x << 16); acc[1] += __uint_as_float(v.x & 0xffff0000u);
                acc[2] += __uint_as_float(v.y << 16); acc[3] += __uint_as_float(v.y & 0xffff0000u);
                acc[4] += __uint_as_float(v.z << 16); acc[5] += __uint_as_float(v.z & 0xffff0000u);
                acc[6] += __uint_as_float(v.w << 16); acc[7] += __uint_as_float(v.w & 0xffff0000u);
            }
        }
    }
    for (int off = 8; off < 64; off <<= 1)
#pragma unroll
        for (int i = 0; i < 8; i++) acc[i] += __shfl_xor(acc[i], off, 64);
    if (group == 0) {
        int card = t - s;
        float ber = (card > 0) ? (1.0f / (float)card) : 0.f;
        uint4 o;
        o.x = pack2bf(acc[0] * ber, acc[1] * ber);
        o.y = pack2bf(acc[2] * ber, acc[3] * ber);
        o.z = pack2bf(acc[4] * ber, acc[5] * ber);
        o.w = pack2bf(acc[6] * ber, acc[7] * ber);
        ef[(size_t)wid * 8 + gl] = o;
    }
}

// Stage 2: one wave per node; bf16 ef gathers, fp32 residual + output.
__global__ void stage2_kernel(const int* __restrict__ noff, const int* __restrict__ ncsr,
                              const uint4* __restrict__ ef, const float* __restrict__ ew,
                              const float* __restrict__ x, float* __restrict__ out) {
    int wid = (blockIdx.x * 256 + threadIdx.x) >> 6;
    if (wid >= N_NODES) return;
    int lane = threadIdx.x & 63;
    int group = lane >> 3;
    int gl = lane & 7;
    int s = noff[wid], t = noff[wid + 1];
    float acc[8] = {0.f, 0.f, 0.f, 0.f, 0.f, 0.f, 0.f, 0.f};
    float dn = 0.f;
    for (int base = s; base < t; base += 64) {
        bool lv = (base + lane < t);
        int idx_l = lv ? ncsr[base + lane] : 0;
        if (lv) dn += ew[idx_l];
        int cnt = t - base; if (cnt > 64) cnt = 64;
        int steps = (cnt + 7) >> 3;
        for (int j = 0; j < steps; j++) {
            int p = 8 * j + group;
            int mi = __shfl(idx_l, p, 64);
            if (p < cnt) {
                uint4 v = ef[(size_t)mi * 8 + gl];
                acc[0] += __uint_as_float(v.x << 16); acc[1] += __uint_as_float(v.x & 0xffff0000u);
                acc[2] += __uint_as_float(v.y << 16); acc[3] += __uint_as_float(v.y & 0xffff0000u);
                acc[4] += __uint_as_float(v.z << 16); acc[5] += __uint_as_float(v.z & 0xffff0000u);
                acc[6] += __uint_as_float(v.w << 16); acc[7] += __uint_as_float(v.w & 0xffff0000u);
            }
        }
    }
    for (int off = 1; off < 64; off <<= 1) dn += __shfl_xor(dn, off, 64);
    for (int off = 8; off < 64; off <<= 1)
#pragma unroll
        for (int i = 0; i < 8; i++) acc[i] += __shfl_xor(acc[i], off, 64);
    if (group == 0) {
        float dnr = (dn > 0.f) ? (1.0f / dn) : 0.f;
        const float4* x4 = (const float4*)x;
        float4* o4 = (float4*)out;
        float4 a = x4[(size_t)wid * 16 + gl * 2];
        float4 b = x4[(size_t)wid * 16 + gl * 2 + 1];
        float4 ra, rb2;
        ra.x = 0.5f * (a.x + dnr * acc[0]);
        ra.y = 0.5f * (a.y + dnr * acc[1]);
        ra.z = 0.5f * (a.z + dnr * acc[2]);
        ra.w = 0.5f * (a.w + dnr * acc[3]);
        rb2.x = 0.5f * (b.x + dnr * acc[4]);
        rb2.y = 0.5f * (b.y + dnr * acc[5]);
        rb2.z = 0.5f * (b.z + dnr * acc[6]);
        rb2.w = 0.5f * (b.w + dnr * acc[7]);
        o4[(size_t)wid * 16 + gl * 2] = ra;
        o4[(size_t)wid * 16 + gl * 2 + 1] = rb2;
    }
}

extern "C" void kernel_launch(void* const* d_in, const int* in_sizes, int n_in,
                              void* d_out, int out_size, void* d_ws, size_t ws_size,
                              hipStream_t stream) {
    const float* x        = (const float*)d_in[0];
    const int*   node_idx = (const int*)d_in[1];
    const int*   edge_idx = (const int*)d_in[2];
    const float* ew       = (const float*)d_in[3];
    float* out = (float*)d_out;

    char* ws = (char*)d_ws;
    unsigned short* rank_n   = (unsigned short*)(ws + 0);
    unsigned short* rank_e   = (unsigned short*)(ws + 3200000);
    int*            noff     = (int*)(ws + 6400000);
    int*            eoff     = (int*)(ws + 6800016);
    int*            node_csr = (int*)(ws + 7000032);
    int*            edge_csr = (int*)(ws + 13400032);
    // lifetime-overlapped scratch:
    unsigned short* cnt_g = (unsigned short*)(ws + 7000032);  // 9.6MB under csr; dead after replprefix
    unsigned short* rb    = (unsigned short*)(ws + 19800032); // 9.6MB; dead after fill
    int*            pn    = (int*)(ws + 29400032);            // scan scratch; dead after scan_write
    int*            pe    = pn + 32;
    int*            bn    = pn + 64;
    int*            be    = pn + 96;
    int*            tot   = (int*)(ws + 29404128);            // 600KB; dead after scan_write
    unsigned int*   ef    = (unsigned int*)(ws + 0);          // bf16, written post-fill
    unsigned int*   xh    = (unsigned int*)(ws + 19800032);   // bf16, written post-fill

    count_kernel<<<(PN + PE) * SUBR, 1024, 0, stream>>>(node_idx, edge_idx, rank_n, rank_e, cnt_g);
    replprefix_kernel<<<(N_KEYS + 255) / 256, 256, 0, stream>>>(cnt_g, rb, tot);
    scan_partial_kernel<<<N_TILES_N + N_TILES_E, 1024, 0, stream>>>(tot, pn, pe);
    scan_base_kernel<<<1, 128, 0, stream>>>(pn, pe, bn, be, noff, eoff);
    scan_write_kernel<<<N_TILES_N + N_TILES_E, 1024, 0, stream>>>(tot, bn, be, noff, eoff);
    fill_kernel<<<(M_INC + 255) / 256, 256, 0, stream>>>(node_idx, edge_idx, rank_n, rank_e,
                                                         rb, noff, eoff, node_csr, edge_csr);
    cvt_kernel<<<((N_NODES * D_HID / 8) + 255) / 256, 256, 0, stream>>>(x, xh);
    stage1_kernel<<<(N_EDGES * 64 + 255) / 256, 256, 0, stream>>>(eoff, edge_csr,
                                                                  (const uint4*)xh, (uint4*)ef);
    stage2_kernel<<<(N_NODES * 64 + 255) / 256, 256, 0, stream>>>(noff, node_csr,
                                                                  (const uint4*)ef, ew, x, out);
}

// Round 12
// 259.065 us; speedup vs baseline: 1.2583x; 1.1719x over previous
//
#include <hip/hip_runtime.h>

#define N_NODES 100000
#define N_EDGES 50000
#define N_KEYS  150000   // node keys [0,100000) then edge keys [100000,150000)
#define M_INC   1600000
#define D_HID   64

#define SUBR    32       // incidence subranges
#define SUBLEN  50000    // M_INC / SUBR
#define KPART   16384    // keys per LDS partition (64 KB histogram)
#define PN      7        // ceil(100000/16384)
#define PE      4        // ceil(50000/16384)

#define N_TILES_N 25   // ceil(100000/4096)
#define N_TILES_E 13   // ceil(50000/4096)

typedef float v2f __attribute__((ext_vector_type(2)));

// ---- workspace layout (byte offsets, lifetime-overlapped) ----
// rank_n [1.6M u16] @0, rank_e @3200000            -- dead after fill
// ef fp8 [3.2M B]   @0  (3.2MB)                    -- written by stage1 (post-fill)
// noff [100001 int] @6400000 ; eoff @6800016
// node_csr @7000032, edge_csr @13400032            -- cnt_g u16 [9.6MB] overlaps
//                                                     (dead after replprefix)
// rb u16 [9.6MB] @19800032, scan scratch @29400032 -- dead after fill / scan
// xh bf16 [6.4M] @19800032 (12.8MB)                -- written by cvt AFTER fill

__device__ __forceinline__ unsigned pack2bf(float a, float b) {
    unsigned ua = __float_as_uint(a); ua = (ua + 0x7fffu + ((ua >> 16) & 1u)) >> 16;
    unsigned ub = __float_as_uint(b); ub = (ub + 0x7fffu + ((ub >> 16) & 1u)) >> 16;
    return ua | (ub << 16);
}

__device__ __forceinline__ unsigned enc_fp8x4(float a, float b, float c, float d) {
    unsigned r = 0;
    r = __builtin_amdgcn_cvt_pk_fp8_f32(a, b, r, false);
    r = __builtin_amdgcn_cvt_pk_fp8_f32(c, d, r, true);
    return r;
}

// Counting without global atomics: block (p,s) filters subrange s for keys in
// partition p, LDS-atomicAdd gives the subrank (u16), then dumps its histogram.
// KPART=16K (64KB LDS): 11 partitions => 70MB re-read. Regular (cached) loads:
// idx stays L2-hot for fill (nt loads in r11 regressed fill 54->93us).
__global__ __launch_bounds__(1024) void count_kernel(
        const int* __restrict__ node_idx, const int* __restrict__ edge_idx,
        unsigned short* __restrict__ rank_n, unsigned short* __restrict__ rank_e,
        unsigned short* __restrict__ cnt_g) {
    __shared__ unsigned int h[KPART];
    int bid = blockIdx.x;
    const int* idx; unsigned short* rk; int p, s, klim, goff;
    if (bid < PN * SUBR) {
        p = bid / SUBR; s = bid % SUBR;
        idx = node_idx; rk = rank_n; klim = N_NODES; goff = 0;
    } else {
        int b2 = bid - PN * SUBR;
        p = b2 / SUBR; s = b2 % SUBR;
        idx = edge_idx; rk = rank_e; klim = N_EDGES; goff = N_NODES;
    }
    int kbase = p * KPART;
    int t = threadIdx.x;
    for (int i = t; i < KPART; i += 1024) h[i] = 0;
    __syncthreads();
    int mbase = s * SUBLEN;
    const int4* src4 = (const int4*)(idx + mbase);
    for (int i = t; i < SUBLEN / 4; i += 1024) {
        int4 v = src4[i];
        int m0 = mbase + i * 4;
        int k;
        k = v.x - kbase; if ((unsigned)k < KPART) rk[m0 + 0] = (unsigned short)atomicAdd(&h[k], 1u);
        k = v.y - kbase; if ((unsigned)k < KPART) rk[m0 + 1] = (unsigned short)atomicAdd(&h[k], 1u);
        k = v.z - kbase; if ((unsigned)k < KPART) rk[m0 + 2] = (unsigned short)atomicAdd(&h[k], 1u);
        k = v.w - kbase; if ((unsigned)k < KPART) rk[m0 + 3] = (unsigned short)atomicAdd(&h[k], 1u);
    }
    __syncthreads();
    for (int i = t; i < KPART; i += 1024) {
        int key = kbase + i;
        if (key < klim) cnt_g[s * N_KEYS + goff + key] = (unsigned short)h[i];
    }
}

// Per-key prefix over the 32 subrange counts -> rb[s][key] (u16); totals -> tot[key].
__global__ void replprefix_kernel(const unsigned short* __restrict__ cnt_g,
                                  unsigned short* __restrict__ rb, int* __restrict__ tot) {
    int key = blockIdx.x * 256 + threadIdx.x;
    if (key < N_KEYS) {
        int base = 0;
#pragma unroll
        for (int k = 0; k < SUBR; k++) {
            rb[k * N_KEYS + key] = (unsigned short)base;
            base += (int)cnt_g[k * N_KEYS + key];
        }
        tot[key] = base;
    }
}

// Scan stage 1: per-tile (4096 elements) sums over the contiguous totals array.
__global__ void scan_partial_kernel(const int* __restrict__ cnt,
                                    int* __restrict__ pn, int* __restrict__ pe) {
    __shared__ int lds[16];
    int b = blockIdx.x;
    const int* src; int nElem; int tile; int* dst;
    if (b < N_TILES_N) { src = cnt;            nElem = N_NODES; tile = b;             dst = pn; }
    else               { src = cnt + N_NODES;  nElem = N_EDGES; tile = b - N_TILES_N; dst = pe; }
    int t = threadIdx.x;
    int i4 = tile * 1024 + t;
    int sum = 0;
    if (i4 * 4 < nElem) {
        int4 v = ((const int4*)src)[i4];
        sum = v.x + v.y + v.z + v.w;
    }
    for (int off = 1; off < 64; off <<= 1) sum += __shfl_xor(sum, off, 64);
    if ((t & 63) == 0) lds[t >> 6] = sum;
    __syncthreads();
    if (t < 16) {
        int s = lds[t];
        for (int off = 1; off < 16; off <<= 1) s += __shfl_xor(s, off, 64);
        if (t == 0) dst[tile] = s;
    }
}

// Scan stage 2: exclusive scan of tile sums; writes sentinel offsets.
__global__ void scan_base_kernel(const int* __restrict__ pn, const int* __restrict__ pe,
                                 int* __restrict__ bn, int* __restrict__ be,
                                 int* __restrict__ noff, int* __restrict__ eoff) {
    int w = threadIdx.x >> 6;
    int lane = threadIdx.x & 63;
    if (w == 0) {
        int v = (lane < N_TILES_N) ? pn[lane] : 0;
        int incl = v;
        for (int d = 1; d < 64; d <<= 1) { int u = __shfl_up(incl, d, 64); if (lane >= d) incl += u; }
        if (lane < N_TILES_N) bn[lane] = incl - v;
        if (lane == N_TILES_N - 1) noff[N_NODES] = incl;
    } else {
        int v = (lane < N_TILES_E) ? pe[lane] : 0;
        int incl = v;
        for (int d = 1; d < 64; d <<= 1) { int u = __shfl_up(incl, d, 64); if (lane >= d) incl += u; }
        if (lane < N_TILES_E) be[lane] = incl - v;
        if (lane == N_TILES_E - 1) eoff[N_EDGES] = incl;
    }
}

// Scan stage 3: block-level exclusive scan of each tile + tile base, int4 I/O.
__global__ void scan_write_kernel(const int* __restrict__ cnt,
                                  const int* __restrict__ bn, const int* __restrict__ be,
                                  int* __restrict__ noff, int* __restrict__ eoff) {
    __shared__ int wsum[16];
    int b = blockIdx.x;
    const int* src; int* dst; int nElem; int tile; int tbase;
    if (b < N_TILES_N) { src = cnt;           dst = noff; nElem = N_NODES; tile = b;             tbase = bn[tile]; }
    else               { src = cnt + N_NODES; dst = eoff; nElem = N_EDGES; tile = b - N_TILES_N; tbase = be[tile]; }
    int t = threadIdx.x;
    int lane = t & 63, w = t >> 6;
    int i4 = tile * 1024 + t;
    int4 c = make_int4(0, 0, 0, 0);
    bool valid = (i4 * 4 < nElem);
    if (valid) c = ((const int4*)src)[i4];
    int tsum = c.x + c.y + c.z + c.w;
    int incl = tsum;
    for (int d = 1; d < 64; d <<= 1) { int u = __shfl_up(incl, d, 64); if (lane >= d) incl += u; }
    if (lane == 63) wsum[w] = incl;
    __syncthreads();
    if (t < 16) {
        int v = wsum[t];
        int wi = v;
        for (int d = 1; d < 16; d <<= 1) { int u = __shfl_up(wi, d, 64); if (t >= d) wi += u; }
        wsum[t] = wi - v;
    }
    __syncthreads();
    int ex = tbase + wsum[w] + incl - tsum;
    if (valid) {
        int4 o;
        o.x = ex; o.y = ex + c.x; o.z = o.y + c.y; o.w = o.z + c.z;
        ((int4*)dst)[i4] = o;
    }
}

// Fill: atomic-free scatter. Slot = seg_off + subrange_base + subrank.
__global__ void fill_kernel(const int* __restrict__ node_idx,
                            const int* __restrict__ edge_idx,
                            const unsigned short* __restrict__ rank_n,
                            const unsigned short* __restrict__ rank_e,
                            const unsigned short* __restrict__ rb,
                            const int* __restrict__ noff, const int* __restrict__ eoff,
                            int* __restrict__ node_csr, int* __restrict__ edge_csr) {
    int m = blockIdx.x * 256 + threadIdx.x;
    if (m < M_INC) {
        int s = m / SUBLEN;
        const unsigned short* rbs = rb + s * N_KEYS;
        int n = node_idx[m], e = edge_idx[m];
        node_csr[noff[n] + (int)rbs[n] + (int)rank_n[m]] = e;
        edge_csr[eoff[e] + (int)rbs[N_NODES + e] + (int)rank_e[m]] = n;
    }
}

// Convert x (fp32) -> xh (bf16, RNE). 8 elements / thread, coalesced.
__global__ void cvt_kernel(const float* __restrict__ x, unsigned int* __restrict__ xh) {
    int i = blockIdx.x * 256 + threadIdx.x;           // 8-element group
    if (i < (N_NODES * D_HID) / 8) {
        const float4* x4 = (const float4*)x;
        float4 a = x4[i * 2], b = x4[i * 2 + 1];
        uint4 o;
        o.x = pack2bf(a.x, a.y); o.y = pack2bf(a.z, a.w);
        o.z = pack2bf(b.x, b.y); o.w = pack2bf(b.z, b.w);
        ((uint4*)xh)[i] = o;
    }
}

// Stage 1: one wave per edge; 8 member-groups x 8 lanes, 16B (8 bf16) per lane.
// Output ef in fp8 e4m3 (8B per lane): row = 64B, whole ef = 3.2MB (fits one
// XCD L2) -> halves stage2's gather traffic.
__global__ void stage1_kernel(const int* __restrict__ eoff, const int* __restrict__ ecsr,
                              const uint4* __restrict__ xh, uint2* __restrict__ ef) {
    int wid = (blockIdx.x * 256 + threadIdx.x) >> 6;
    if (wid >= N_EDGES) return;
    int lane = threadIdx.x & 63;
    int group = lane >> 3;
    int gl = lane & 7;
    int s = eoff[wid], t = eoff[wid + 1];
    float acc[8] = {0.f, 0.f, 0.f, 0.f, 0.f, 0.f, 0.f, 0.f};
    for (int base = s; base < t; base += 64) {
        int idx_l = (base + lane < t) ? ecsr[base + lane] : 0;
        int cnt = t - base; if (cnt > 64) cnt = 64;
        int steps = (cnt + 7) >> 3;
        for (int j = 0; j < steps; j++) {
            int p = 8 * j + group;
            int mi = __shfl(idx_l, p, 64);
            if (p < cnt) {
                uint4 v = xh[(size_t)mi * 8 + gl];
                acc[0] += __uint_as_float(v.x << 16); acc[1] += __uint_as_float(v.x & 0xffff0000u);
                acc[2] += __uint_as_float(v.y << 16); acc[3] += __uint_as_float(v.y & 0xffff0000u);
                acc[4] += __uint_as_float(v.z << 16); acc[5] += __uint_as_float(v.z & 0xffff0000u);
                acc[6] += __uint_as_float(v.w << 16); acc[7] += __uint_as_float(v.w & 0xffff0000u);
            }
        }
    }
    for (int off = 8; off < 64; off <<= 1)
#pragma unroll
        for (int i = 0; i < 8; i++) acc[i] += __shfl_xor(acc[i], off, 64);
    if (group == 0) {
        int card = t - s;
        float ber = (card > 0) ? (1.0f / (float)card) : 0.f;
        uint2 o;
        o.x = enc_fp8x4(acc[0] * ber, acc[1] * ber, acc[2] * ber, acc[3] * ber);
        o.y = enc_fp8x4(acc[4] * ber, acc[5] * ber, acc[6] * ber, acc[7] * ber);
        ef[(size_t)wid * 8 + gl] = o;
    }
}

// Stage 2: one wave per node; fp8 ef gathers (8B/lane), fp32 residual + output.
__global__ void stage2_kernel(const int* __restrict__ noff, const int* __restrict__ ncsr,
                              const uint2* __restrict__ ef, const float* __restrict__ ew,
                              const float* __restrict__ x, float* __restrict__ out) {
    int wid = (blockIdx.x * 256 + threadIdx.x) >> 6;
    if (wid >= N_NODES) return;
    int lane = threadIdx.x & 63;
    int group = lane >> 3;
    int gl = lane & 7;
    int s = noff[wid], t = noff[wid + 1];
    float acc[8] = {0.f, 0.f, 0.f, 0.f, 0.f, 0.f, 0.f, 0.f};
    float dn = 0.f;
    for (int base = s; base < t; base += 64) {
        bool lv = (base + lane < t);
        int idx_l = lv ? ncsr[base + lane] : 0;
        if (lv) dn += ew[idx_l];
        int cnt = t - base; if (cnt > 64) cnt = 64;
        int steps = (cnt + 7) >> 3;
        for (int j = 0; j < steps; j++) {
            int p = 8 * j + group;
            int mi = __shfl(idx_l, p, 64);
            if (p < cnt) {
                uint2 v = ef[(size_t)mi * 8 + gl];
                v2f d0 = __builtin_amdgcn_cvt_pk_f32_fp8(v.x, false);
                v2f d1 = __builtin_amdgcn_cvt_pk_f32_fp8(v.x, true);
                v2f d2 = __builtin_amdgcn_cvt_pk_f32_fp8(v.y, false);
                v2f d3 = __builtin_amdgcn_cvt_pk_f32_fp8(v.y, true);
                acc[0] += d0.x; acc[1] += d0.y; acc[2] += d1.x; acc[3] += d1.y;
                acc[4] += d2.x; acc[5] += d2.y; acc[6] += d3.x; acc[7] += d3.y;
            }
        }
    }
    for (int off = 1; off < 64; off <<= 1) dn += __shfl_xor(dn, off, 64);
    for (int off = 8; off < 64; off <<= 1)
#pragma unroll
        for (int i = 0; i < 8; i++) acc[i] += __shfl_xor(acc[i], off, 64);
    if (group == 0) {
        float dnr = (dn > 0.f) ? (1.0f / dn) : 0.f;
        const float4* x4 = (const float4*)x;
        float4* o4 = (float4*)out;
        float4 a = x4[(size_t)wid * 16 + gl * 2];
        float4 b = x4[(size_t)wid * 16 + gl * 2 + 1];
        float4 ra, rb2;
        ra.x = 0.5f * (a.x + dnr * acc[0]);
        ra.y = 0.5f * (a.y + dnr * acc[1]);
        ra.z = 0.5f * (a.z + dnr * acc[2]);
        ra.w = 0.5f * (a.w + dnr * acc[3]);
        rb2.x = 0.5f * (b.x + dnr * acc[4]);
        rb2.y = 0.5f * (b.y + dnr * acc[5]);
        rb2.z = 0.5f * (b.z + dnr * acc[6]);
        rb2.w = 0.5f * (b.w + dnr * acc[7]);
        o4[(size_t)wid * 16 + gl * 2] = ra;
        o4[(size_t)wid * 16 + gl * 2 + 1] = rb2;
    }
}

extern "C" void kernel_launch(void* const* d_in, const int* in_sizes, int n_in,
                              void* d_out, int out_size, void* d_ws, size_t ws_size,
                              hipStream_t stream) {
    const float* x        = (const float*)d_in[0];
    const int*   node_idx = (const int*)d_in[1];
    const int*   edge_idx = (const int*)d_in[2];
    const float* ew       = (const float*)d_in[3];
    float* out = (float*)d_out;

    char* ws = (char*)d_ws;
    unsigned short* rank_n   = (unsigned short*)(ws + 0);
    unsigned short* rank_e   = (unsigned short*)(ws + 3200000);
    int*            noff     = (int*)(ws + 6400000);
    int*            eoff     = (int*)(ws + 6800016);
    int*            node_csr = (int*)(ws + 7000032);
    int*            edge_csr = (int*)(ws + 13400032);
    // lifetime-overlapped scratch:
    unsigned short* cnt_g = (unsigned short*)(ws + 7000032);  // 9.6MB under csr; dead after replprefix
    unsigned short* rb    = (unsigned short*)(ws + 19800032); // 9.6MB; dead after fill
    int*            pn    = (int*)(ws + 29400032);            // scan scratch; dead after scan_write
    int*            pe    = pn + 32;
    int*            bn    = pn + 64;
    int*            be    = pn + 96;
    int*            tot   = (int*)(ws + 29404128);            // 600KB; dead after scan_write
    unsigned int*   ef    = (unsigned int*)(ws + 0);          // fp8, written post-fill (3.2MB)
    unsigned int*   xh    = (unsigned int*)(ws + 19800032);   // bf16, written post-fill

    count_kernel<<<(PN + PE) * SUBR, 1024, 0, stream>>>(node_idx, edge_idx, rank_n, rank_e, cnt_g);
    replprefix_kernel<<<(N_KEYS + 255) / 256, 256, 0, stream>>>(cnt_g, rb, tot);
    scan_partial_kernel<<<N_TILES_N + N_TILES_E, 1024, 0, stream>>>(tot, pn, pe);
    scan_base_kernel<<<1, 128, 0, stream>>>(pn, pe, bn, be, noff, eoff);
    scan_write_kernel<<<N_TILES_N + N_TILES_E, 1024, 0, stream>>>(tot, bn, be, noff, eoff);
    fill_kernel<<<(M_INC + 255) / 256, 256, 0, stream>>>(node_idx, edge_idx, rank_n, rank_e,
                                                         rb, noff, eoff, node_csr, edge_csr);
    cvt_kernel<<<((N_NODES * D_HID / 8) + 255) / 256, 256, 0, stream>>>(x, xh);
    stage1_kernel<<<(N_EDGES * 64 + 255) / 256, 256, 0, stream>>>(eoff, edge_csr,
                                                                  (const uint4*)xh, (uint2*)ef);
    stage2_kernel<<<(N_NODES * 64 + 255) / 256, 256, 0, stream>>>(noff, node_csr,
                                                                  (const uint2*)ef, ew, x, out);
}

// Round 13
// 257.544 us; speedup vs baseline: 1.2657x; 1.0059x over previous
//
#include <hip/hip_runtime.h>

#define N_NODES 100000
#define N_EDGES 50000
#define N_KEYS  150000   // node keys [0,100000) then edge keys [100000,150000)
#define M_INC   1600000
#define D_HID   64

#define SUBR    32       // incidence subranges
#define SUBLEN  50000    // M_INC / SUBR
#define KPART   16384    // keys per LDS partition (64 KB histogram)
#define PN      7        // ceil(100000/16384)
#define PE      4        // ceil(50000/16384)

#define N_TILES_N 25   // ceil(100000/4096)
#define N_TILES_E 13   // ceil(50000/4096)

typedef float v2f __attribute__((ext_vector_type(2)));

// ---- workspace layout (byte offsets, lifetime-overlapped) ----
// rank_n [1.6M u16] @0, rank_e @3200000            -- dead after fill
// ef fp8 [3.2MB]    @0                             -- written by stage1 (post-fill)
// noff [100001 int] @6400000 ; eoff @6800016
// node_csr @7000032, edge_csr @13400032            -- cnt_g u16 [9.6MB] overlaps
//                                                     (dead after replprefix)
// rb u16 [9.6MB] @19800032, scan scratch @29400032 -- dead after fill / scan
// xh fp8 [6.4MB] @19800032                         -- written by cvt AFTER fill

__device__ __forceinline__ unsigned enc_fp8x4(float a, float b, float c, float d) {
    unsigned r = 0;
    r = __builtin_amdgcn_cvt_pk_fp8_f32(a, b, r, false);
    r = __builtin_amdgcn_cvt_pk_fp8_f32(c, d, r, true);
    return r;
}

// Counting without global atomics: block (p,s) filters subrange s for keys in
// partition p, LDS-atomicAdd gives the subrank (u16), then dumps its histogram.
// Regular (cached) loads: idx must stay L2-hot for fill (r11: nt loads here
// regressed fill 54->93us).
__global__ __launch_bounds__(1024) void count_kernel(
        const int* __restrict__ node_idx, const int* __restrict__ edge_idx,
        unsigned short* __restrict__ rank_n, unsigned short* __restrict__ rank_e,
        unsigned short* __restrict__ cnt_g) {
    __shared__ unsigned int h[KPART];
    int bid = blockIdx.x;
    const int* idx; unsigned short* rk; int p, s, klim, goff;
    if (bid < PN * SUBR) {
        p = bid / SUBR; s = bid % SUBR;
        idx = node_idx; rk = rank_n; klim = N_NODES; goff = 0;
    } else {
        int b2 = bid - PN * SUBR;
        p = b2 / SUBR; s = b2 % SUBR;
        idx = edge_idx; rk = rank_e; klim = N_EDGES; goff = N_NODES;
    }
    int kbase = p * KPART;
    int t = threadIdx.x;
    for (int i = t; i < KPART; i += 1024) h[i] = 0;
    __syncthreads();
    int mbase = s * SUBLEN;
    const int4* src4 = (const int4*)(idx + mbase);
    for (int i = t; i < SUBLEN / 4; i += 1024) {
        int4 v = src4[i];
        int m0 = mbase + i * 4;
        int k;
        k = v.x - kbase; if ((unsigned)k < KPART) rk[m0 + 0] = (unsigned short)atomicAdd(&h[k], 1u);
        k = v.y - kbase; if ((unsigned)k < KPART) rk[m0 + 1] = (unsigned short)atomicAdd(&h[k], 1u);
        k = v.z - kbase; if ((unsigned)k < KPART) rk[m0 + 2] = (unsigned short)atomicAdd(&h[k], 1u);
        k = v.w - kbase; if ((unsigned)k < KPART) rk[m0 + 3] = (unsigned short)atomicAdd(&h[k], 1u);
    }
    __syncthreads();
    for (int i = t; i < KPART; i += 1024) {
        int key = kbase + i;
        if (key < klim) cnt_g[s * N_KEYS + goff + key] = (unsigned short)h[i];
    }
}

// Per-key prefix over the 32 subrange counts -> rb[s][key] (u16); totals -> tot[key].
__global__ void replprefix_kernel(const unsigned short* __restrict__ cnt_g,
                                  unsigned short* __restrict__ rb, int* __restrict__ tot) {
    int key = blockIdx.x * 256 + threadIdx.x;
    if (key < N_KEYS) {
        int base = 0;
#pragma unroll
        for (int k = 0; k < SUBR; k++) {
            rb[k * N_KEYS + key] = (unsigned short)base;
            base += (int)cnt_g[k * N_KEYS + key];
        }
        tot[key] = base;
    }
}

// Scan stage 1: per-tile (4096 elements) sums over the contiguous totals array.
__global__ void scan_partial_kernel(const int* __restrict__ cnt,
                                    int* __restrict__ pn, int* __restrict__ pe) {
    __shared__ int lds[16];
    int b = blockIdx.x;
    const int* src; int nElem; int tile; int* dst;
    if (b < N_TILES_N) { src = cnt;            nElem = N_NODES; tile = b;             dst = pn; }
    else               { src = cnt + N_NODES;  nElem = N_EDGES; tile = b - N_TILES_N; dst = pe; }
    int t = threadIdx.x;
    int i4 = tile * 1024 + t;
    int sum = 0;
    if (i4 * 4 < nElem) {
        int4 v = ((const int4*)src)[i4];
        sum = v.x + v.y + v.z + v.w;
    }
    for (int off = 1; off < 64; off <<= 1) sum += __shfl_xor(sum, off, 64);
    if ((t & 63) == 0) lds[t >> 6] = sum;
    __syncthreads();
    if (t < 16) {
        int s = lds[t];
        for (int off = 1; off < 16; off <<= 1) s += __shfl_xor(s, off, 64);
        if (t == 0) dst[tile] = s;
    }
}

// Scan stage 2: exclusive scan of tile sums; writes sentinel offsets.
__global__ void scan_base_kernel(const int* __restrict__ pn, const int* __restrict__ pe,
                                 int* __restrict__ bn, int* __restrict__ be,
                                 int* __restrict__ noff, int* __restrict__ eoff) {
    int w = threadIdx.x >> 6;
    int lane = threadIdx.x & 63;
    if (w == 0) {
        int v = (lane < N_TILES_N) ? pn[lane] : 0;
        int incl = v;
        for (int d = 1; d < 64; d <<= 1) { int u = __shfl_up(incl, d, 64); if (lane >= d) incl += u; }
        if (lane < N_TILES_N) bn[lane] = incl - v;
        if (lane == N_TILES_N - 1) noff[N_NODES] = incl;
    } else {
        int v = (lane < N_TILES_E) ? pe[lane] : 0;
        int incl = v;
        for (int d = 1; d < 64; d <<= 1) { int u = __shfl_up(incl, d, 64); if (lane >= d) incl += u; }
        if (lane < N_TILES_E) be[lane] = incl - v;
        if (lane == N_TILES_E - 1) eoff[N_EDGES] = incl;
    }
}

// Scan stage 3: block-level exclusive scan of each tile + tile base, int4 I/O.
__global__ void scan_write_kernel(const int* __restrict__ cnt,
                                  const int* __restrict__ bn, const int* __restrict__ be,
                                  int* __restrict__ noff, int* __restrict__ eoff) {
    __shared__ int wsum[16];
    int b = blockIdx.x;
    const int* src; int* dst; int nElem; int tile; int tbase;
    if (b < N_TILES_N) { src = cnt;           dst = noff; nElem = N_NODES; tile = b;             tbase = bn[tile]; }
    else               { src = cnt + N_NODES; dst = eoff; nElem = N_EDGES; tile = b - N_TILES_N; tbase = be[tile]; }
    int t = threadIdx.x;
    int lane = t & 63, w = t >> 6;
    int i4 = tile * 1024 + t;
    int4 c = make_int4(0, 0, 0, 0);
    bool valid = (i4 * 4 < nElem);
    if (valid) c = ((const int4*)src)[i4];
    int tsum = c.x + c.y + c.z + c.w;
    int incl = tsum;
    for (int d = 1; d < 64; d <<= 1) { int u = __shfl_up(incl, d, 64); if (lane >= d) incl += u; }
    if (lane == 63) wsum[w] = incl;
    __syncthreads();
    if (t < 16) {
        int v = wsum[t];
        int wi = v;
        for (int d = 1; d < 16; d <<= 1) { int u = __shfl_up(wi, d, 64); if (t >= d) wi += u; }
        wsum[t] = wi - v;
    }
    __syncthreads();
    int ex = tbase + wsum[w] + incl - tsum;
    if (valid) {
        int4 o;
        o.x = ex; o.y = ex + c.x; o.z = o.y + c.y; o.w = o.z + c.z;
        ((int4*)dst)[i4] = o;
    }
}

// Fill: atomic-free scatter, 4 incidences/thread with int4/ushort4 loads.
// Batches never straddle subranges (SUBLEN % 4 == 0).
__global__ void fill_kernel(const int* __restrict__ node_idx,
                            const int* __restrict__ edge_idx,
                            const unsigned short* __restrict__ rank_n,
                            const unsigned short* __restrict__ rank_e,
                            const unsigned short* __restrict__ rb,
                            const int* __restrict__ noff, const int* __restrict__ eoff,
                            int* __restrict__ node_csr, int* __restrict__ edge_csr) {
    int q = blockIdx.x * 256 + threadIdx.x;      // batch of 4 incidences
    if (q < M_INC / 4) {
        int m0 = q * 4;
        int s = m0 / SUBLEN;
        const unsigned short* rbs = rb + s * N_KEYS;
        int4 nv = ((const int4*)node_idx)[q];
        int4 ev = ((const int4*)edge_idx)[q];
        ushort4 rn = ((const ushort4*)rank_n)[q];
        ushort4 re = ((const ushort4*)rank_e)[q];
        node_csr[noff[nv.x] + (int)rbs[nv.x] + (int)rn.x] = ev.x;
        node_csr[noff[nv.y] + (int)rbs[nv.y] + (int)rn.y] = ev.y;
        node_csr[noff[nv.z] + (int)rbs[nv.z] + (int)rn.z] = ev.z;
        node_csr[noff[nv.w] + (int)rbs[nv.w] + (int)rn.w] = ev.w;
        edge_csr[eoff[ev.x] + (int)rbs[N_NODES + ev.x] + (int)re.x] = nv.x;
        edge_csr[eoff[ev.y] + (int)rbs[N_NODES + ev.y] + (int)re.y] = nv.y;
        edge_csr[eoff[ev.z] + (int)rbs[N_NODES + ev.z] + (int)re.z] = nv.z;
        edge_csr[eoff[ev.w] + (int)rbs[N_NODES + ev.w] + (int)re.w] = nv.w;
    }
}

// Convert x (fp32) -> xh (fp8 e4m3, HW RNE). 8 elements / thread, coalesced.
__global__ void cvt_kernel(const float* __restrict__ x, uint2* __restrict__ xh) {
    int i = blockIdx.x * 256 + threadIdx.x;           // 8-element group
    if (i < (N_NODES * D_HID) / 8) {
        const float4* x4 = (const float4*)x;
        float4 a = x4[i * 2], b = x4[i * 2 + 1];
        uint2 o;
        o.x = enc_fp8x4(a.x, a.y, a.z, a.w);
        o.y = enc_fp8x4(b.x, b.y, b.z, b.w);
        xh[i] = o;
    }
}

// Stage 1: one wave per edge; 8 member-groups x 8 lanes, 8B (8 fp8) per lane.
// Output ef in fp8 (row = 64B, ef total 3.2MB).
__global__ void stage1_kernel(const int* __restrict__ eoff, const int* __restrict__ ecsr,
                              const uint2* __restrict__ xh, uint2* __restrict__ ef) {
    int wid = (blockIdx.x * 256 + threadIdx.x) >> 6;
    if (wid >= N_EDGES) return;
    int lane = threadIdx.x & 63;
    int group = lane >> 3;
    int gl = lane & 7;
    int s = eoff[wid], t = eoff[wid + 1];
    float acc[8] = {0.f, 0.f, 0.f, 0.f, 0.f, 0.f, 0.f, 0.f};
    for (int base = s; base < t; base += 64) {
        int idx_l = (base + lane < t) ? ecsr[base + lane] : 0;
        int cnt = t - base; if (cnt > 64) cnt = 64;
        int steps = (cnt + 7) >> 3;
        for (int j = 0; j < steps; j++) {
            int p = 8 * j + group;
            int mi = __shfl(idx_l, p, 64);
            if (p < cnt) {
                uint2 v = xh[(size_t)mi * 8 + gl];
                v2f d0 = __builtin_amdgcn_cvt_pk_f32_fp8(v.x, false);
                v2f d1 = __builtin_amdgcn_cvt_pk_f32_fp8(v.x, true);
                v2f d2 = __builtin_amdgcn_cvt_pk_f32_fp8(v.y, false);
                v2f d3 = __builtin_amdgcn_cvt_pk_f32_fp8(v.y, true);
                acc[0] += d0.x; acc[1] += d0.y; acc[2] += d1.x; acc[3] += d1.y;
                acc[4] += d2.x; acc[5] += d2.y; acc[6] += d3.x; acc[7] += d3.y;
            }
        }
    }
    for (int off = 8; off < 64; off <<= 1)
#pragma unroll
        for (int i = 0; i < 8; i++) acc[i] += __shfl_xor(acc[i], off, 64);
    if (group == 0) {
        int card = t - s;
        float ber = (card > 0) ? (1.0f / (float)card) : 0.f;
        uint2 o;
        o.x = enc_fp8x4(acc[0] * ber, acc[1] * ber, acc[2] * ber, acc[3] * ber);
        o.y = enc_fp8x4(acc[4] * ber, acc[5] * ber, acc[6] * ber, acc[7] * ber);
        ef[(size_t)wid * 8 + gl] = o;
    }
}

// Stage 2: one wave per node; fp8 ef gathers (8B/lane), fp32 residual + output.
__global__ void stage2_kernel(const int* __restrict__ noff, const int* __restrict__ ncsr,
                              const uint2* __restrict__ ef, const float* __restrict__ ew,
                              const float* __restrict__ x, float* __restrict__ out) {
    int wid = (blockIdx.x * 256 + threadIdx.x) >> 6;
    if (wid >= N_NODES) return;
    int lane = threadIdx.x & 63;
    int group = lane >> 3;
    int gl = lane & 7;
    int s = noff[wid], t = noff[wid + 1];
    float acc[8] = {0.f, 0.f, 0.f, 0.f, 0.f, 0.f, 0.f, 0.f};
    float dn = 0.f;
    for (int base = s; base < t; base += 64) {
        bool lv = (base + lane < t);
        int idx_l = lv ? ncsr[base + lane] : 0;
        if (lv) dn += ew[idx_l];
        int cnt = t - base; if (cnt > 64) cnt = 64;
        int steps = (cnt + 7) >> 3;
        for (int j = 0; j < steps; j++) {
            int p = 8 * j + group;
            int mi = __shfl(idx_l, p, 64);
            if (p < cnt) {
                uint2 v = ef[(size_t)mi * 8 + gl];
                v2f d0 = __builtin_amdgcn_cvt_pk_f32_fp8(v.x, false);
                v2f d1 = __builtin_amdgcn_cvt_pk_f32_fp8(v.x, true);
                v2f d2 = __builtin_amdgcn_cvt_pk_f32_fp8(v.y, false);
                v2f d3 = __builtin_amdgcn_cvt_pk_f32_fp8(v.y, true);
                acc[0] += d0.x; acc[1] += d0.y; acc[2] += d1.x; acc[3] += d1.y;
                acc[4] += d2.x; acc[5] += d2.y; acc[6] += d3.x; acc[7] += d3.y;
            }
        }
    }
    for (int off = 1; off < 64; off <<= 1) dn += __shfl_xor(dn, off, 64);
    for (int off = 8; off < 64; off <<= 1)
#pragma unroll
        for (int i = 0; i < 8; i++) acc[i] += __shfl_xor(acc[i], off, 64);
    if (group == 0) {
        float dnr = (dn > 0.f) ? (1.0f / dn) : 0.f;
        const float4* x4 = (const float4*)x;
        float4* o4 = (float4*)out;
        float4 a = x4[(size_t)wid * 16 + gl * 2];
        float4 b = x4[(size_t)wid * 16 + gl * 2 + 1];
        float4 ra, rb2;
        ra.x = 0.5f * (a.x + dnr * acc[0]);
        ra.y = 0.5f * (a.y + dnr * acc[1]);
        ra.z = 0.5f * (a.z + dnr * acc[2]);
        ra.w = 0.5f * (a.w + dnr * acc[3]);
        rb2.x = 0.5f * (b.x + dnr * acc[4]);
        rb2.y = 0.5f * (b.y + dnr * acc[5]);
        rb2.z = 0.5f * (b.z + dnr * acc[6]);
        rb2.w = 0.5f * (b.w + dnr * acc[7]);
        o4[(size_t)wid * 16 + gl * 2] = ra;
        o4[(size_t)wid * 16 + gl * 2 + 1] = rb2;
    }
}

extern "C" void kernel_launch(void* const* d_in, const int* in_sizes, int n_in,
                              void* d_out, int out_size, void* d_ws, size_t ws_size,
                              hipStream_t stream) {
    const float* x        = (const float*)d_in[0];
    const int*   node_idx = (const int*)d_in[1];
    const int*   edge_idx = (const int*)d_in[2];
    const float* ew       = (const float*)d_in[3];
    float* out = (float*)d_out;

    char* ws = (char*)d_ws;
    unsigned short* rank_n   = (unsigned short*)(ws + 0);
    unsigned short* rank_e   = (unsigned short*)(ws + 3200000);
    int*            noff     = (int*)(ws + 6400000);
    int*            eoff     = (int*)(ws + 6800016);
    int*            node_csr = (int*)(ws + 7000032);
    int*            edge_csr = (int*)(ws + 13400032);
    // lifetime-overlapped scratch:
    unsigned short* cnt_g = (unsigned short*)(ws + 7000032);  // 9.6MB under csr; dead after replprefix
    unsigned short* rb    = (unsigned short*)(ws + 19800032); // 9.6MB; dead after fill
    int*            pn    = (int*)(ws + 29400032);            // scan scratch; dead after scan_write
    int*            pe    = pn + 32;
    int*            bn    = pn + 64;
    int*            be    = pn + 96;
    int*            tot   = (int*)(ws + 29404128);            // 600KB; dead after scan_write
    uint2*          ef    = (uint2*)(ws + 0);                 // fp8, written post-fill (3.2MB)
    uint2*          xh    = (uint2*)(ws + 19800032);          // fp8, written post-fill (6.4MB)

    count_kernel<<<(PN + PE) * SUBR, 1024, 0, stream>>>(node_idx, edge_idx, rank_n, rank_e, cnt_g);
    replprefix_kernel<<<(N_KEYS + 255) / 256, 256, 0, stream>>>(cnt_g, rb, tot);
    scan_partial_kernel<<<N_TILES_N + N_TILES_E, 1024, 0, stream>>>(tot, pn, pe);
    scan_base_kernel<<<1, 128, 0, stream>>>(pn, pe, bn, be, noff, eoff);
    scan_write_kernel<<<N_TILES_N + N_TILES_E, 1024, 0, stream>>>(tot, bn, be, noff, eoff);
    fill_kernel<<<(M_INC / 4 + 255) / 256, 256, 0, stream>>>(node_idx, edge_idx, rank_n, rank_e,
                                                             rb, noff, eoff, node_csr, edge_csr);
    cvt_kernel<<<((N_NODES * D_HID / 8) + 255) / 256, 256, 0, stream>>>(x, xh);
    stage1_kernel<<<(N_EDGES * 64 + 255) / 256, 256, 0, stream>>>(eoff, edge_csr, xh, ef);
    stage2_kernel<<<(N_NODES * 64 + 255) / 256, 256, 0, stream>>>(noff, node_csr, ef, ew, x, out);
}